// Round 2
// baseline (1417.233 us; speedup 1.0000x reference)
//
#include <hip/hip_runtime.h>
#include <hip/hip_bf16.h>

// Problem constants (from reference)
#define NN   100000   // nodes
#define NE   600000   // edges
#define INC  128      // in channels
#define HC   128      // heads*per_head = 2*64
#define NH   2        // heads
#define CPH  64       // channels per head
#define TDIM 64       // time enc dim
#define MSGD 64       // msg dim
#define EDD  128      // edge_attr dim = TDIM + MSGD

typedef __hip_bfloat16 bf16;

static __device__ __forceinline__ float b2f(bf16 h) { return __bfloat162float(h); }
static __device__ __forceinline__ bf16  f2b(float f) { return __float2bfloat16(f); }
static __device__ __forceinline__ float2 bload2(const bf16* p) {
    __hip_bfloat162 h = *reinterpret_cast<const __hip_bfloat162*>(p);
    return __bfloat1622float2(h);
}
static __device__ __forceinline__ void bstore2(bf16* p, float a, float b) {
    __hip_bfloat162 h;
    h.x = __float2bfloat16(a);
    h.y = __float2bfloat16(b);
    *reinterpret_cast<__hip_bfloat162*>(p) = h;
}
// total-order int encoding of float for atomicMax
static __device__ __forceinline__ int   f2ord(float f) { int i = __float_as_int(f); return i >= 0 ? i : i ^ 0x7fffffff; }
static __device__ __forceinline__ float ord2f(int i)   { return __int_as_float(i >= 0 ? i : i ^ 0x7fffffff); }

// ---------------------------------------------------------------------------
// K0: init amax (-inf encoded) and denom (0). Dedicated kernel so init can
// never be hostage to a launch failure of a big-LDS kernel.
// ---------------------------------------------------------------------------
__global__ __launch_bounds__(256) void k0_init(int* __restrict__ amax, float* __restrict__ denom)
{
    int tid = blockIdx.x * 256 + threadIdx.x;
    if (tid < NN * NH) { amax[tid] = f2ord(-1e30f); denom[tid] = 0.0f; }
}

// ---------------------------------------------------------------------------
// K1: node projections q,k,v (bf16 to ws) and skip (f32 into out_acc).
// 64 nodes per block; x staged in LDS (32 KB); W streamed from global (L1/L2).
// 8 nodes x 4 cols per thread.
// ---------------------------------------------------------------------------
#define TN 64
__global__ __launch_bounds__(256) void k1_node_proj(
    const float* __restrict__ x,
    const float* __restrict__ Wq, const float* __restrict__ bq,
    const float* __restrict__ Wk, const float* __restrict__ bk,
    const float* __restrict__ Wv, const float* __restrict__ bv,
    const float* __restrict__ Wsk, const float* __restrict__ bsk,
    bf16* __restrict__ qn, bf16* __restrict__ kn, bf16* __restrict__ vn,
    float* __restrict__ out_acc)
{
    __shared__ float xs[TN][INC];      // 32 KB

    int tid = threadIdx.x;
    int n0 = blockIdx.x * TN;

    // stage x tile (float4)
    for (int idx = tid; idx < TN * INC / 4; idx += 256) {
        int nn = idx >> 5;       // 32 float4 per row
        int c4 = idx & 31;
        int node = n0 + nn;
        float4 v;
        if (node < NN) v = reinterpret_cast<const float4*>(x)[(size_t)node * (INC / 4) + c4];
        else           v = make_float4(0.f, 0.f, 0.f, 0.f);
        *reinterpret_cast<float4*>(&xs[nn][c4 * 4]) = v;
    }
    __syncthreads();

    const float* Ws[4] = {Wq, Wk, Wv, Wsk};
    const float* Bs[4] = {bq, bk, bv, bsk};
    int colb = (tid & 31) * 4;   // 4 consecutive output cols
    int rowb = (tid >> 5) * 8;   // 8 nodes

    for (int g = 0; g < 4; ++g) {
        const float* W = Ws[g];
        float acc[8][4];
        #pragma unroll
        for (int a = 0; a < 8; ++a)
            #pragma unroll
            for (int b = 0; b < 4; ++b) acc[a][b] = 0.0f;

        #pragma unroll 4
        for (int kk = 0; kk < INC; ++kk) {
            float4 w = *reinterpret_cast<const float4*>(&W[kk * HC + colb]);
            #pragma unroll
            for (int a = 0; a < 8; ++a) {
                float xv = xs[rowb + a][kk];
                acc[a][0] = fmaf(xv, w.x, acc[a][0]);
                acc[a][1] = fmaf(xv, w.y, acc[a][1]);
                acc[a][2] = fmaf(xv, w.z, acc[a][2]);
                acc[a][3] = fmaf(xv, w.w, acc[a][3]);
            }
        }

        float b0 = Bs[g][colb];
        float b1 = Bs[g][colb + 1];
        float b2v = Bs[g][colb + 2];
        float b3 = Bs[g][colb + 3];

        if (g < 3) {
            bf16* dstp = (g == 0) ? qn : (g == 1) ? kn : vn;
            #pragma unroll
            for (int a = 0; a < 8; ++a) {
                int node = n0 + rowb + a;
                if (node < NN) {
                    bstore2(&dstp[node * HC + colb],     acc[a][0] + b0, acc[a][1] + b1);
                    bstore2(&dstp[node * HC + colb + 2], acc[a][2] + b2v, acc[a][3] + b3);
                }
            }
        } else {
            #pragma unroll
            for (int a = 0; a < 8; ++a) {
                int node = n0 + rowb + a;
                if (node < NN) {
                    float4 o;
                    o.x = acc[a][0] + b0; o.y = acc[a][1] + b1;
                    o.z = acc[a][2] + b2v; o.w = acc[a][3] + b3;
                    *reinterpret_cast<float4*>(&out_acc[node * HC + colb]) = o;
                }
            }
        }
    }
}

// ---------------------------------------------------------------------------
// K2: per-edge pass. One wave per edge. Builds edge_attr = [cos(rel_t*wt+bt), msg]
// in LDS, computes e = edge_attr @ We (We staged bf16 in LDS), alpha per head,
// stores e (bf16) and alpha (f32), atomicMax into amax.
// LDS: 32 KB We + 2 KB ea + 0.5 KB wt/bt = 34.5 KB (well under limit).
// ---------------------------------------------------------------------------
__global__ __launch_bounds__(256) void k2_edge_alpha(
    const int* __restrict__ eidx,
    const float* __restrict__ lu, const float* __restrict__ t, const float* __restrict__ msg,
    const float* __restrict__ wt, const float* __restrict__ bt,
    const float* __restrict__ We,
    const bf16* __restrict__ qn, const bf16* __restrict__ kn,
    bf16* __restrict__ e_ws, float* __restrict__ alpha, int* __restrict__ amax)
{
    __shared__ bf16  We_s[EDD * HC];   // 32 KB (bf16-converted)
    __shared__ float wt_s[TDIM], bt_s[TDIM];
    __shared__ float ea_s[4][EDD];     // per-wave edge_attr

    int tid = threadIdx.x;
    for (int idx = tid; idx < EDD * HC; idx += 256) We_s[idx] = f2b(We[idx]);
    if (tid < TDIM) { wt_s[tid] = wt[tid]; bt_s[tid] = bt[tid]; }
    __syncthreads();

    int wave = tid >> 6, lane = tid & 63;
    int gw = blockIdx.x * 4 + wave;
    int nw = gridDim.x * 4;
    int niter = (NE + nw - 1) / nw;

    for (int it = 0; it < niter; ++it) {
        int e = gw + it * nw;
        bool act = (e < NE);          // wave-uniform
        int srcn = 0, dstn = 0;
        if (act) {
            srcn = eidx[e];
            dstn = eidx[NE + e];
            float rel = lu[srcn] - t[e];
            ea_s[wave][lane]        = cosf(fmaf(rel, wt_s[lane], bt_s[lane]));
            ea_s[wave][TDIM + lane] = msg[(size_t)e * MSGD + lane];
        }
        __syncthreads();
        if (act) {
            float e0 = 0.0f, e1 = 0.0f;
            #pragma unroll 8
            for (int d = 0; d < EDD; ++d) {
                float ad = ea_s[wave][d];
                float2 w = bload2(&We_s[d * HC + 2 * lane]);
                e0 = fmaf(ad, w.x, e0);
                e1 = fmaf(ad, w.y, e1);
            }
            float2 qv = bload2(&qn[(size_t)dstn * HC + 2 * lane]);
            float2 kv = bload2(&kn[(size_t)srcn * HC + 2 * lane]);
            float part = qv.x * (kv.x + e0) + qv.y * (kv.y + e1);
            // reduce within each 32-lane half (per head)
            part += __shfl_xor(part, 1);
            part += __shfl_xor(part, 2);
            part += __shfl_xor(part, 4);
            part += __shfl_xor(part, 8);
            part += __shfl_xor(part, 16);
            if ((lane & 31) == 0) {
                int h = lane >> 5;
                float a = part * 0.125f;   // 1/sqrt(64)
                alpha[e * NH + h] = a;
                atomicMax(&amax[dstn * NH + h], f2ord(a));
            }
            bstore2(&e_ws[(size_t)e * HC + 2 * lane], e0, e1);
        }
        __syncthreads();
    }
}

// ---------------------------------------------------------------------------
// K3: ex = exp(alpha - amax[dst]); alpha <- ex; denom[dst] += ex
// ---------------------------------------------------------------------------
__global__ __launch_bounds__(256) void k3_softmax(
    const int* __restrict__ eidx, const int* __restrict__ amax,
    float* __restrict__ alpha, float* __restrict__ denom)
{
    int tid = blockIdx.x * 256 + threadIdx.x;
    if (tid >= NE * NH) return;
    int e = tid >> 1, h = tid & 1;
    int dstn = eidx[NE + e];
    float m = ord2f(amax[dstn * NH + h]);
    // mirrors reference's isfinite() replacement; also guards poison
    if (!(m > -1e29f && m < 1e29f)) m = 0.0f;
    float ex = expf(alpha[tid] - m);
    alpha[tid] = ex;
    atomicAdd(&denom[dstn * NH + h], ex);
}

// ---------------------------------------------------------------------------
// K4: out_acc[dst,c] += attn * (v[src,c] + e[edge,c])
// ---------------------------------------------------------------------------
__global__ __launch_bounds__(256) void k4_agg(
    const int* __restrict__ eidx, const float* __restrict__ alpha,
    const float* __restrict__ denom, const bf16* __restrict__ vn,
    const bf16* __restrict__ e_ws, float* __restrict__ out_acc)
{
    int tid = blockIdx.x * 256 + threadIdx.x;
    if (tid >= NE * HC) return;
    int e = tid >> 7, c = tid & 127, h = c >> 6;
    int dstn = eidx[NE + e];
    int srcn = eidx[e];
    float ex  = alpha[e * NH + h];
    float den = denom[dstn * NH + h];
    float attn = ex / (den + 1e-16f);
    float vj = b2f(vn[(size_t)srcn * HC + c]) + b2f(e_ws[tid]);
    atomicAdd(&out_acc[dstn * HC + c], attn * vj);
}

// ---------------------------------------------------------------------------
// K5: f32 accumulator -> f32 output
// ---------------------------------------------------------------------------
__global__ __launch_bounds__(256) void k5_final(
    const float* __restrict__ out_acc, float* __restrict__ out)
{
    int tid = blockIdx.x * 256 + threadIdx.x;
    if (tid < NN * HC) out[tid] = out_acc[tid];
}

// ---------------------------------------------------------------------------
extern "C" void kernel_launch(void* const* d_in, const int* in_sizes, int n_in,
                              void* d_out, int out_size, void* d_ws, size_t ws_size,
                              hipStream_t stream)
{
    const float* x   = (const float*)d_in[0];
    const float* lu  = (const float*)d_in[1];
    const int*   eidx= (const int*)d_in[2];
    const float* t   = (const float*)d_in[3];
    const float* msg = (const float*)d_in[4];
    const float* wt  = (const float*)d_in[5];
    const float* bt  = (const float*)d_in[6];
    const float* Wq  = (const float*)d_in[7];
    const float* bq  = (const float*)d_in[8];
    const float* Wk  = (const float*)d_in[9];
    const float* bk  = (const float*)d_in[10];
    const float* Wv  = (const float*)d_in[11];
    const float* bv  = (const float*)d_in[12];
    const float* We  = (const float*)d_in[13];
    const float* Wsk = (const float*)d_in[14];
    const float* bsk = (const float*)d_in[15];
    float* out = (float*)d_out;

    // workspace layout (total ~288 MB)
    char* ws = (char*)d_ws;
    size_t off = 0;
    bf16*  qn      = (bf16*)(ws + off);  off += (size_t)NN * HC * 2;   // 25.6 MB
    bf16*  kn      = (bf16*)(ws + off);  off += (size_t)NN * HC * 2;   // 25.6 MB
    bf16*  vn      = (bf16*)(ws + off);  off += (size_t)NN * HC * 2;   // 25.6 MB
    float* out_acc = (float*)(ws + off); off += (size_t)NN * HC * 4;   // 51.2 MB
    float* alpha   = (float*)(ws + off); off += (size_t)NE * NH * 4;   // 4.8 MB
    int*   amax    = (int*)(ws + off);   off += (size_t)NN * NH * 4;   // 0.8 MB
    float* denom   = (float*)(ws + off); off += (size_t)NN * NH * 4;   // 0.8 MB
    bf16*  e_ws    = (bf16*)(ws + off);  off += (size_t)NE * HC * 2;   // 153.6 MB

    k0_init<<<(NN * NH + 255) / 256, 256, 0, stream>>>(amax, denom);

    k1_node_proj<<<(NN + TN - 1) / TN, 256, 0, stream>>>(
        x, Wq, bq, Wk, bk, Wv, bv, Wsk, bsk, qn, kn, vn, out_acc);

    k2_edge_alpha<<<1024, 256, 0, stream>>>(
        eidx, lu, t, msg, wt, bt, We, qn, kn, e_ws, alpha, amax);

    k3_softmax<<<(NE * NH + 255) / 256, 256, 0, stream>>>(eidx, amax, alpha, denom);

    k4_agg<<<(NE * HC) / 256, 256, 0, stream>>>(eidx, alpha, denom, vn, e_ws, out_acc);

    k5_final<<<(NN * HC + 255) / 256, 256, 0, stream>>>(out_acc, out);
}

// Round 3
// 1156.413 us; speedup vs baseline: 1.2255x; 1.2255x over previous
//
#include <hip/hip_runtime.h>
#include <hip/hip_bf16.h>

// Problem constants (from reference)
#define NN   100000   // nodes
#define NE   600000   // edges
#define INC  128      // in channels
#define HC   128      // heads*per_head = 2*64
#define NH   2        // heads
#define TDIM 64       // time enc dim
#define MSGD 64       // msg dim
#define EDD  128      // edge_attr dim = TDIM + MSGD

#define EPB  64       // edges per block (K2 tile M)
#define NPB  64       // nodes per block (K1 tile M)
#define LDK  (EDD + 8)  // padded row (bf16 elems) for A/B operand tiles
#define LDC  (HC + 8)   // padded row for C tiles

typedef __hip_bfloat16 bf16;
typedef __attribute__((ext_vector_type(8))) short short8;
typedef __attribute__((ext_vector_type(4))) float floatx4;

static __device__ __forceinline__ float b2f(bf16 h) { return __bfloat162float(h); }
static __device__ __forceinline__ bf16  f2b(float f) { return __float2bfloat16(f); }
static __device__ __forceinline__ float2 bload2(const bf16* p) {
    __hip_bfloat162 h = *reinterpret_cast<const __hip_bfloat162*>(p);
    return __bfloat1622float2(h);
}
// total-order int encoding of float for atomicMax
static __device__ __forceinline__ int   f2ord(float f) { int i = __float_as_int(f); return i >= 0 ? i : i ^ 0x7fffffff; }
static __device__ __forceinline__ float ord2f(int i)   { return __int_as_float(i >= 0 ? i : i ^ 0x7fffffff); }

// ---------------------------------------------------------------------------
// K0: init amax (-inf encoded) and denom (0)
// ---------------------------------------------------------------------------
__global__ __launch_bounds__(256) void k0_init(int* __restrict__ amax, float* __restrict__ denom)
{
    int tid = blockIdx.x * 256 + threadIdx.x;
    if (tid < NN * NH) { amax[tid] = f2ord(-1e30f); denom[tid] = 0.0f; }
}

// ---------------------------------------------------------------------------
// K0b: transpose + bf16-convert the 5 weight matrices: wT[mat][n][k] = W[mat][k][n]
// (so MFMA B-fragments read contiguous k for a fixed output col n)
// ---------------------------------------------------------------------------
__global__ __launch_bounds__(256) void k0b_transpose(
    const float* __restrict__ Wq, const float* __restrict__ Wk,
    const float* __restrict__ Wv, const float* __restrict__ Wsk,
    const float* __restrict__ We, bf16* __restrict__ wT)
{
    int tid = blockIdx.x * 256 + threadIdx.x;
    if (tid >= 5 * 128 * 128) return;
    int mat = tid >> 14;
    int n = (tid >> 7) & 127;
    int k = tid & 127;
    const float* W = (mat == 0) ? Wq : (mat == 1) ? Wk : (mat == 2) ? Wv : (mat == 3) ? Wsk : We;
    wT[tid] = f2b(W[k * 128 + n]);
    (void)n;
}

// ---------------------------------------------------------------------------
// K1: node projections via MFMA. 64 nodes x 128 cols per block; g-loop over
// {Wq,Wk,Wv,Wskip}. x tile bf16 in LDS (A-op layout), Wt bf16 in LDS (B-op).
// q/k/v -> bf16 (LDS-assembled coalesced stores); skip -> f32 out_acc direct.
// ---------------------------------------------------------------------------
__global__ __launch_bounds__(256) void k1_node_proj(
    const float* __restrict__ x, const bf16* __restrict__ wT,
    const float* __restrict__ bq, const float* __restrict__ bk,
    const float* __restrict__ bv, const float* __restrict__ bsk,
    bf16* __restrict__ qn, bf16* __restrict__ kn, bf16* __restrict__ vn,
    float* __restrict__ out_acc)
{
    __shared__ __align__(16) bf16 xs[NPB * LDK];    // 17.4 KB
    __shared__ __align__(16) bf16 wts[HC * LDK];    // 34.8 KB
    __shared__ __align__(16) bf16 outs[NPB * LDC];  // 17.4 KB
    __shared__ float bias_s[HC];

    int tid = threadIdx.x;
    int lane = tid & 63, wave = tid >> 6;
    int n0node = blockIdx.x * NPB;

    // stage x tile as bf16 (A-operand layout [m][k], padded)
    for (int idx = tid; idx < NPB * (INC / 4); idx += 256) {
        int m = idx >> 5, c4 = idx & 31;
        int node = n0node + m;
        float4 v = (node < NN) ? reinterpret_cast<const float4*>(x)[(size_t)node * 32 + c4]
                               : make_float4(0.f, 0.f, 0.f, 0.f);
        union { bf16 h[4]; uint2 u; } pk;
        pk.h[0] = f2b(v.x); pk.h[1] = f2b(v.y); pk.h[2] = f2b(v.z); pk.h[3] = f2b(v.w);
        *reinterpret_cast<uint2*>(&xs[m * LDK + c4 * 4]) = pk.u;
    }

    const float* Bs[4] = {bq, bk, bv, bsk};
    bf16* Os[3] = {qn, kn, vn};
    int m0 = wave * 16, r = lane & 15, quad = lane >> 4;

    for (int g = 0; g < 4; ++g) {
        __syncthreads();  // xs ready / previous g's wts+outs consumers done
        const bf16* WgT = wT + (size_t)g * 128 * 128;
        for (int idx = tid; idx < HC * (EDD / 8); idx += 256) {
            int n = idx >> 4, seg = idx & 15;
            *reinterpret_cast<uint4*>(&wts[n * LDK + seg * 8]) =
                *reinterpret_cast<const uint4*>(WgT + n * 128 + seg * 8);
        }
        if (tid < HC) bias_s[tid] = Bs[g][tid];
        __syncthreads();

        floatx4 acc[8];
        #pragma unroll
        for (int i = 0; i < 8; ++i) acc[i] = (floatx4){0.f, 0.f, 0.f, 0.f};

        #pragma unroll
        for (int k0 = 0; k0 < 128; k0 += 32) {
            short8 a = *reinterpret_cast<const short8*>(&xs[(m0 + r) * LDK + k0 + quad * 8]);
            #pragma unroll
            for (int nt = 0; nt < 8; ++nt) {
                short8 b = *reinterpret_cast<const short8*>(&wts[(nt * 16 + r) * LDK + k0 + quad * 8]);
                acc[nt] = __builtin_amdgcn_mfma_f32_16x16x32_bf16(a, b, acc[nt], 0, 0, 0);
            }
        }

        if (g < 3) {
            // C layout: col=lane&15, row=quad*4+reg  -> assemble in LDS, then coalesced store
            #pragma unroll
            for (int nt = 0; nt < 8; ++nt) {
                int col = nt * 16 + r;
                float bsv = bias_s[col];
                #pragma unroll
                for (int rg = 0; rg < 4; ++rg) {
                    int row = m0 + quad * 4 + rg;
                    outs[row * LDC + col] = f2b(acc[nt][rg] + bsv);
                }
            }
            __syncthreads();
            bf16* dst = Os[g];
            for (int idx = tid; idx < NPB * (HC / 8); idx += 256) {
                int row = idx >> 4, seg = idx & 15;
                int node = n0node + row;
                if (node < NN)
                    *reinterpret_cast<uint4*>(dst + (size_t)node * HC + seg * 8) =
                        *reinterpret_cast<const uint4*>(&outs[row * LDC + seg * 8]);
            }
        } else {
            // skip: f32 direct stores (16 lanes x 4B = 64B segments)
            #pragma unroll
            for (int nt = 0; nt < 8; ++nt) {
                int col = nt * 16 + r;
                float bsv = bias_s[col];
                #pragma unroll
                for (int rg = 0; rg < 4; ++rg) {
                    int node = n0node + m0 + quad * 4 + rg;
                    if (node < NN) out_acc[(size_t)node * HC + col] = acc[nt][rg] + bsv;
                }
            }
        }
    }
}

// ---------------------------------------------------------------------------
// K2: edge pass via MFMA. 64 edges x 128 cols per block.
// Stage edge_attr=[cos(rel*wt+bt), msg] bf16 (A-op), WeT bf16 (B-op),
// MFMA -> e tile; e -> LDS (epilogue + coalesced e_ws store);
// alpha = q[dst].(k[src]+e)/8 via shuffle-reduce; atomicMax amax.
// ---------------------------------------------------------------------------
__global__ __launch_bounds__(256) void k2_edge_alpha(
    const int* __restrict__ eidx,
    const float* __restrict__ lu, const float* __restrict__ t, const float* __restrict__ msg,
    const float* __restrict__ wtv, const float* __restrict__ btv,
    const bf16* __restrict__ WeT,
    const bf16* __restrict__ qn, const bf16* __restrict__ kn,
    bf16* __restrict__ e_ws, float* __restrict__ alpha, int* __restrict__ amax)
{
    __shared__ __align__(16) bf16 wts[HC * LDK];    // 34.8 KB
    __shared__ __align__(16) bf16 ea_s[EPB * LDK];  // 17.4 KB
    __shared__ __align__(16) bf16 e_s[EPB * LDC];   // 17.4 KB
    __shared__ float wt_s[TDIM], bt_s[TDIM];
    __shared__ float rel_s[EPB];
    __shared__ int src_s[EPB], dst_s[EPB];

    int tid = threadIdx.x;
    int lane = tid & 63, wave = tid >> 6;
    int e0 = blockIdx.x * EPB;   // NE % EPB == 0, no guards needed

    for (int idx = tid; idx < HC * (EDD / 8); idx += 256) {
        int n = idx >> 4, seg = idx & 15;
        *reinterpret_cast<uint4*>(&wts[n * LDK + seg * 8]) =
            *reinterpret_cast<const uint4*>(WeT + n * 128 + seg * 8);
    }
    if (tid < TDIM) { wt_s[tid] = wtv[tid]; bt_s[tid] = btv[tid]; }
    if (tid < EPB) {
        int s = eidx[e0 + tid];
        int d = eidx[NE + e0 + tid];
        src_s[tid] = s; dst_s[tid] = d;
        rel_s[tid] = lu[s] - t[e0 + tid];
    }
    __syncthreads();

    // build edge_attr tile (bf16, A-operand layout)
    for (int idx = tid; idx < EPB * EDD; idx += 256) {
        int m = idx >> 7, d = idx & 127;
        float v;
        if (d < TDIM) v = cosf(fmaf(rel_s[m], wt_s[d], bt_s[d]));
        else          v = msg[(size_t)(e0 + m) * MSGD + (d - TDIM)];
        ea_s[m * LDK + d] = f2b(v);
    }
    __syncthreads();

    floatx4 acc[8];
    #pragma unroll
    for (int i = 0; i < 8; ++i) acc[i] = (floatx4){0.f, 0.f, 0.f, 0.f};
    int m0 = wave * 16, r = lane & 15, quad = lane >> 4;

    #pragma unroll
    for (int k0 = 0; k0 < 128; k0 += 32) {
        short8 a = *reinterpret_cast<const short8*>(&ea_s[(m0 + r) * LDK + k0 + quad * 8]);
        #pragma unroll
        for (int nt = 0; nt < 8; ++nt) {
            short8 b = *reinterpret_cast<const short8*>(&wts[(nt * 16 + r) * LDK + k0 + quad * 8]);
            acc[nt] = __builtin_amdgcn_mfma_f32_16x16x32_bf16(a, b, acc[nt], 0, 0, 0);
        }
    }

    // e tile -> LDS (bf16)
    #pragma unroll
    for (int nt = 0; nt < 8; ++nt) {
        int col = nt * 16 + r;
        #pragma unroll
        for (int rg = 0; rg < 4; ++rg) {
            int row = m0 + quad * 4 + rg;
            e_s[row * LDC + col] = f2b(acc[nt][rg]);
        }
    }
    __syncthreads();

    // coalesced e_ws store
    for (int idx = tid; idx < EPB * (HC / 8); idx += 256) {
        int row = idx >> 4, seg = idx & 15;
        *reinterpret_cast<uint4*>(e_ws + (size_t)(e0 + row) * HC + seg * 8) =
            *reinterpret_cast<const uint4*>(&e_s[row * LDC + seg * 8]);
    }

    // alpha epilogue: each wave does its 16 edges
    for (int i = 0; i < 16; ++i) {
        int m = m0 + i;
        int srcn = src_s[m], dstn = dst_s[m];
        float2 qv = bload2(&qn[(size_t)dstn * HC + 2 * lane]);
        float2 kv = bload2(&kn[(size_t)srcn * HC + 2 * lane]);
        float2 ev = bload2(&e_s[m * LDC + 2 * lane]);
        float part = qv.x * (kv.x + ev.x) + qv.y * (kv.y + ev.y);
        part += __shfl_xor(part, 1);
        part += __shfl_xor(part, 2);
        part += __shfl_xor(part, 4);
        part += __shfl_xor(part, 8);
        part += __shfl_xor(part, 16);
        if ((lane & 31) == 0) {
            int h = lane >> 5;
            float a = part * 0.125f;   // 1/sqrt(64)
            alpha[(size_t)(e0 + m) * NH + h] = a;
            atomicMax(&amax[dstn * NH + h], f2ord(a));
        }
    }
}

// ---------------------------------------------------------------------------
// K3: ex = exp(alpha - amax[dst]); alpha <- ex; denom[dst] += ex
// ---------------------------------------------------------------------------
__global__ __launch_bounds__(256) void k3_softmax(
    const int* __restrict__ eidx, const int* __restrict__ amax,
    float* __restrict__ alpha, float* __restrict__ denom)
{
    int tid = blockIdx.x * 256 + threadIdx.x;
    if (tid >= NE * NH) return;
    int e = tid >> 1, h = tid & 1;
    int dstn = eidx[NE + e];
    float m = ord2f(amax[dstn * NH + h]);
    if (!(m > -1e29f && m < 1e29f)) m = 0.0f;   // mirrors reference isfinite()
    float ex = expf(alpha[tid] - m);
    alpha[tid] = ex;
    atomicAdd(&denom[dstn * NH + h], ex);
}

// ---------------------------------------------------------------------------
// K4: out_acc[dst,c] += attn * (v[src,c] + e[edge,c])
// ---------------------------------------------------------------------------
__global__ __launch_bounds__(256) void k4_agg(
    const int* __restrict__ eidx, const float* __restrict__ alpha,
    const float* __restrict__ denom, const bf16* __restrict__ vn,
    const bf16* __restrict__ e_ws, float* __restrict__ out_acc)
{
    int tid = blockIdx.x * 256 + threadIdx.x;
    if (tid >= NE * HC) return;
    int e = tid >> 7, c = tid & 127, h = c >> 6;
    int dstn = eidx[NE + e];
    int srcn = eidx[e];
    float ex  = alpha[e * NH + h];
    float den = denom[dstn * NH + h];
    float attn = ex / (den + 1e-16f);
    float vj = b2f(vn[(size_t)srcn * HC + c]) + b2f(e_ws[tid]);
    atomicAdd(&out_acc[dstn * HC + c], attn * vj);
}

// ---------------------------------------------------------------------------
// K5: f32 accumulator -> f32 output
// ---------------------------------------------------------------------------
__global__ __launch_bounds__(256) void k5_final(
    const float* __restrict__ out_acc, float* __restrict__ out)
{
    int tid = blockIdx.x * 256 + threadIdx.x;
    if (tid < NN * HC) out[tid] = out_acc[tid];
}

// ---------------------------------------------------------------------------
extern "C" void kernel_launch(void* const* d_in, const int* in_sizes, int n_in,
                              void* d_out, int out_size, void* d_ws, size_t ws_size,
                              hipStream_t stream)
{
    const float* x   = (const float*)d_in[0];
    const float* lu  = (const float*)d_in[1];
    const int*   eidx= (const int*)d_in[2];
    const float* t   = (const float*)d_in[3];
    const float* msg = (const float*)d_in[4];
    const float* wt  = (const float*)d_in[5];
    const float* bt  = (const float*)d_in[6];
    const float* Wq  = (const float*)d_in[7];
    const float* bq  = (const float*)d_in[8];
    const float* Wk  = (const float*)d_in[9];
    const float* bk  = (const float*)d_in[10];
    const float* Wv  = (const float*)d_in[11];
    const float* bv  = (const float*)d_in[12];
    const float* We  = (const float*)d_in[13];
    const float* Wsk = (const float*)d_in[14];
    const float* bsk = (const float*)d_in[15];
    float* out = (float*)d_out;

    // workspace layout
    char* ws = (char*)d_ws;
    size_t off = 0;
    bf16*  qn      = (bf16*)(ws + off);  off += (size_t)NN * HC * 2;   // 25.6 MB
    bf16*  kn      = (bf16*)(ws + off);  off += (size_t)NN * HC * 2;   // 25.6 MB
    bf16*  vn      = (bf16*)(ws + off);  off += (size_t)NN * HC * 2;   // 25.6 MB
    float* out_acc = (float*)(ws + off); off += (size_t)NN * HC * 4;   // 51.2 MB
    float* alpha   = (float*)(ws + off); off += (size_t)NE * NH * 4;   // 4.8 MB
    int*   amax    = (int*)(ws + off);   off += (size_t)NN * NH * 4;   // 0.8 MB
    float* denom   = (float*)(ws + off); off += (size_t)NN * NH * 4;   // 0.8 MB
    bf16*  e_ws    = (bf16*)(ws + off);  off += (size_t)NE * HC * 2;   // 153.6 MB
    bf16*  wT      = (bf16*)(ws + off);  off += (size_t)5 * 128 * 128 * 2; // 0.16 MB

    k0_init<<<(NN * NH + 255) / 256, 256, 0, stream>>>(amax, denom);

    k0b_transpose<<<(5 * 128 * 128) / 256, 256, 0, stream>>>(Wq, Wk, Wv, Wsk, We, wT);

    k1_node_proj<<<(NN + NPB - 1) / NPB, 256, 0, stream>>>(
        x, wT, bq, bk, bv, bsk, qn, kn, vn, out_acc);

    k2_edge_alpha<<<NE / EPB, 256, 0, stream>>>(
        eidx, lu, t, msg, wt, bt, wT + (size_t)4 * 128 * 128,
        qn, kn, e_ws, alpha, amax);

    k3_softmax<<<(NE * NH + 255) / 256, 256, 0, stream>>>(eidx, amax, alpha, denom);

    k4_agg<<<(NE * HC) / 256, 256, 0, stream>>>(eidx, alpha, denom, vn, e_ws, out_acc);

    k5_final<<<(NN * HC + 255) / 256, 256, 0, stream>>>(out_acc, out);
}